// Round 1
// 243.293 us; speedup vs baseline: 1.0267x; 1.0267x over previous
//
#include <hip/hip_runtime.h>
#include <math.h>

#define BB 32
#define PP 2048
#define CC 512
#define TT 128            // PP/16
#define NROWS (BB*PP)     // 65536

// One block per (b,t) tile: 16 rows x 512 channels = 32 KB.
// Fuses mean + 27-tap gate stencil + sigmoid + scale in a single pass.
// x is read once into registers and held across the reductions; the only
// re-reads are the 32 halo rows (t-1, t+1 planes), which neighboring
// blocks share -> L2/L3 hits with the XCD-chunked block swizzle.
__global__ __launch_bounds__(256) void fused_kernel(
        const float* __restrict__ x,
        const float* __restrict__ w1, const float* __restrict__ w2,
        const float* __restrict__ w3, float* __restrict__ out) {
    __shared__ float smean[3][16];   // planes t-1 / t / t+1
    __shared__ float spart[4][8];    // per-wave row partials
    __shared__ float sgate[16];

    // XCD-aware swizzle: 4096 blocks, 8 XCDs, 512 contiguous per XCD.
    int bid = blockIdx.x;
    int wg  = ((bid & 7) << 9) | (bid >> 3);
    int b = wg >> 7;          // /128
    int t = wg & 127;

    int tid  = threadIdx.x;
    int wave = tid >> 6;
    int lane = tid & 63;

    size_t tile_f4 = ((size_t)(b * TT + t) * 16) * (CC / 4);  // float4 offset
    const float4* xt = (const float4*)x + tile_f4;
    float4*       ot = (float4*)out     + tile_f4;

    // ---- own tile: 8 coalesced float4 loads per thread, held in regs ----
    float4 v[8];
    #pragma unroll
    for (int j = 0; j < 8; ++j) v[j] = xt[tid + 256 * j];

    // ---- halo rows: 32 rows (16 of t-1, 16 of t+1), 8 threads per row ----
    int hr    = tid >> 3;          // 0..31
    int hu    = tid & 7;
    int plane = hr >> 4;           // 0: t-1, 1: t+1
    int rloc  = hr & 15;
    int ht    = t + (plane ? 1 : -1);
    bool hvalid = (ht >= 0) && (ht < TT);
    float hsum = 0.0f;
    if (hvalid) {
        const float4* hrow = (const float4*)x +
            ((size_t)(b * TT + ht) * 16 + rloc) * (CC / 4);
        #pragma unroll
        for (int j = 0; j < 16; ++j) {
            float4 hv = hrow[hu + 8 * j];
            hsum += (hv.x + hv.y) + (hv.z + hv.w);
        }
    }

    if (tid < 48) ((float*)smean)[tid] = 0.0f;

    // ---- own-row means: waves 0,1 hold even rows (2j), waves 2,3 odd (2j+1) ----
    #pragma unroll
    for (int j = 0; j < 8; ++j) {
        float s = (v[j].x + v[j].y) + (v[j].z + v[j].w);
        #pragma unroll
        for (int off = 32; off > 0; off >>= 1)
            s += __shfl_down(s, off, 64);
        if (lane == 0) spart[wave][j] = s;
    }

    // ---- halo: reduce 8 lanes per row ----
    hsum += __shfl_down(hsum, 4, 64);
    hsum += __shfl_down(hsum, 2, 64);
    hsum += __shfl_down(hsum, 1, 64);

    __syncthreads();   // spart complete, smean zero-initialized

    if (hu == 0 && hvalid)
        smean[plane ? 2 : 0][rloc] = hsum * (1.0f / 512.0f);
    if (tid < 16) {
        int jj = tid >> 1;   // row r maps to j = r>>1
        float s = (tid & 1) ? (spart[2][jj] + spart[3][jj])
                            : (spart[0][jj] + spart[1][jj]);
        smean[1][tid] = s * (1.0f / 512.0f);
    }

    __syncthreads();   // all 48 means ready

    // ---- gate: 27-tap combined stencil, one thread per row ----
    if (tid < 16) {
        int h  = tid >> 2;
        int w_ = tid & 3;
        float g = 0.0f;
        #pragma unroll
        for (int i = 0; i < 3; ++i) {
            #pragma unroll
            for (int j = 0; j < 3; ++j) {
                int hh = h + j - 1;
                if (hh < 0 || hh > 3) continue;
                #pragma unroll
                for (int k = 0; k < 3; ++k) {
                    int ww = w_ + k - 1;
                    if (ww < 0 || ww > 3) continue;
                    float wt = w3[i * 9 + j * 3 + k];
                    if (i < 2 && j < 2 && k < 2) wt += w2[i * 4 + j * 2 + k];
                    if (i == 1 && j == 1 && k == 1) wt += w1[0];
                    g += wt * smean[i][hh * 4 + ww];
                }
            }
        }
        sgate[tid] = 1.0f / (1.0f + __expf(-g));
    }

    __syncthreads();

    // ---- scale from held registers, coalesced float4 store ----
    #pragma unroll
    for (int j = 0; j < 8; ++j) {
        float s = sgate[(tid + 256 * j) >> 7];
        float4 o = v[j];
        o.x *= s; o.y *= s; o.z *= s; o.w *= s;
        ot[tid + 256 * j] = o;
    }
}

extern "C" void kernel_launch(void* const* d_in, const int* in_sizes, int n_in,
                              void* d_out, int out_size, void* d_ws, size_t ws_size,
                              hipStream_t stream) {
    const float* x  = (const float*)d_in[0];
    const float* w1 = (const float*)d_in[1];
    const float* w2 = (const float*)d_in[2];
    const float* w3 = (const float*)d_in[3];
    float* out = (float*)d_out;

    fused_kernel<<<BB * TT, 256, 0, stream>>>(x, w1, w2, w3, out);
}